// Round 1
// baseline (154.883 us; speedup 1.0000x reference)
//
#include <hip/hip_runtime.h>

// PhobiaLoss: YOLO-style loss.
// predictions, targets: (B=256, 52, 52, 20) fp32 contiguous. Output: scalar fp32.
// CH=20 = 2 boxes * 5 + 5 classes (channels 15..19 beyond class slice unused;
// class slice is channels 10..14).

constexpr int   kB        = 256;
constexpr int   kGrid     = 52;
constexpr int   kCH       = 20;
constexpr int   kCells    = kB * kGrid * kGrid;       // 692224
constexpr float kAlpha    = 0.25f;
constexpr float kLamCoord = 5.0f;

__global__ __launch_bounds__(256) void phobia_main_kernel(
    const float* __restrict__ pred,
    const float* __restrict__ tgt,
    float* __restrict__ acc)   // acc[0]=coord, acc[1]=conf, acc[2]=cls, acc[3]=nobj
{
    const int cell = blockIdx.x * 256 + threadIdx.x;

    float coord = 0.f, conf = 0.f, cls = 0.f, nobj = 0.f;

    if (cell < kCells) {
        // 20 floats per cell = 80 bytes, 16B-aligned. Load channels 0..15 as 4x float4.
        const float4* p4 = reinterpret_cast<const float4*>(pred) + (size_t)cell * 5;
        const float4* t4 = reinterpret_cast<const float4*>(tgt)  + (size_t)cell * 5;
        const float4 pa = p4[0], pb = p4[1], pc = p4[2], pd = p4[3];
        const float4 ta = t4[0], tb = t4[1], tc4 = t4[2], td = t4[3];

        const float p[16] = {pa.x, pa.y, pa.z, pa.w,  pb.x, pb.y, pb.z, pb.w,
                             pc.x, pc.y, pc.z, pc.w,  pd.x, pd.y, pd.z, pd.w};
        const float t[16] = {ta.x, ta.y, ta.z, ta.w,  tb.x, tb.y, tb.z, tb.w,
                             tc4.x, tc4.y, tc4.z, tc4.w,  td.x, td.y, td.z, td.w};

        float obj_count = 0.f;
        #pragma unroll
        for (int n = 0; n < 2; ++n) {
            const int b5   = n * 5;
            const float l  = p[b5 + 4];     // conf logit
            const float tc = t[b5 + 4];     // conf target
            const float has = (tc > 0.5f) ? 1.f : 0.f;

            // coord: sum of squared diffs over 4 coords, gated by has_obj
            float sq = 0.f;
            #pragma unroll
            for (int k = 0; k < 4; ++k) {
                const float d = p[b5 + k] - t[b5 + k];
                sq += d * d;
            }
            coord += has * sq;

            // focal BCE on confidence
            const float ce = fmaxf(l, 0.f) - l * tc + log1pf(__expf(-fabsf(l)));
            const float s  = 1.f / (1.f + __expf(-l));
            const float pt = s * tc + (1.f - s) * (1.f - tc);
            const float at = kAlpha * tc + (1.f - kAlpha) * (1.f - tc);
            const float om = 1.f - pt;
            conf += at * om * om * ce;

            obj_count += has;
        }
        nobj = obj_count;

        // class NLL: argmax of target channels 10..14 (first-max, strict >),
        // carry the matching pred logit so all register indices stay static.
        float bv = t[10], pv = p[10];
        if (t[11] > bv) { bv = t[11]; pv = p[11]; }
        if (t[12] > bv) { bv = t[12]; pv = p[12]; }
        if (t[13] > bv) { bv = t[13]; pv = p[13]; }
        if (t[14] > bv) { bv = t[14]; pv = p[14]; }

        const float m = fmaxf(fmaxf(fmaxf(p[10], p[11]), fmaxf(p[12], p[13])), p[14]);
        const float se = __expf(p[10] - m) + __expf(p[11] - m) + __expf(p[12] - m)
                       + __expf(p[13] - m) + __expf(p[14] - m);
        const float nll = __logf(se) + m - pv;   // lse - selected logit
        cls = obj_count * nll;
    }

    // Wave (64-lane) butterfly-ish down-reduce
    #pragma unroll
    for (int off = 32; off >= 1; off >>= 1) {
        coord += __shfl_down(coord, off);
        conf  += __shfl_down(conf,  off);
        cls   += __shfl_down(cls,   off);
        nobj  += __shfl_down(nobj,  off);
    }

    __shared__ float sred[4][4];   // [wave][value]
    const int wave = threadIdx.x >> 6;
    const int lane = threadIdx.x & 63;
    if (lane == 0) {
        sred[wave][0] = coord; sred[wave][1] = conf;
        sred[wave][2] = cls;   sred[wave][3] = nobj;
    }
    __syncthreads();
    if (threadIdx.x == 0) {
        float c0 = 0.f, c1 = 0.f, c2 = 0.f, c3 = 0.f;
        #pragma unroll
        for (int w = 0; w < 4; ++w) {
            c0 += sred[w][0]; c1 += sred[w][1];
            c2 += sred[w][2]; c3 += sred[w][3];
        }
        atomicAdd(&acc[0], c0);
        atomicAdd(&acc[1], c1);
        atomicAdd(&acc[2], c2);
        atomicAdd(&acc[3], c3);
    }
}

__global__ void phobia_final_kernel(const float* __restrict__ acc,
                                    float* __restrict__ out)
{
    const float coord = acc[0];
    const float conf  = acc[1];
    const float cls   = acc[2];
    const float nobj  = acc[3];
    out[0] = kLamCoord * (coord / (float)kB)
           + (conf / (float)kB)
           + cls / fmaxf(nobj, 1.f);
}

extern "C" void kernel_launch(void* const* d_in, const int* in_sizes, int n_in,
                              void* d_out, int out_size, void* d_ws, size_t ws_size,
                              hipStream_t stream) {
    const float* pred = (const float*)d_in[0];
    const float* tgt  = (const float*)d_in[1];
    float* acc = (float*)d_ws;
    float* out = (float*)d_out;

    hipMemsetAsync(acc, 0, 4 * sizeof(float), stream);

    const int blocks = (kCells + 255) / 256;   // 2704
    phobia_main_kernel<<<blocks, 256, 0, stream>>>(pred, tgt, acc);
    phobia_final_kernel<<<1, 1, 0, stream>>>(acc, out);
}